// Round 17
// baseline (188.124 us; speedup 1.0000x reference)
//
#include <hip/hip_runtime.h>

#define MTOT 32768
#define KC   4096
#define DDIM 256
#define BM   128          // rows per block, phase 1
#define ZELEMS (MTOT * DDIM)
#define THRESH 2.0e-4f
#define WLCAP 8192
#define RGRID 2048        // rescore grid

typedef _Float16 half8 __attribute__((ext_vector_type(8)));
typedef float f32x4 __attribute__((ext_vector_type(4)));

__device__ __forceinline__ void gload_lds16(const void* g, void* l) {
  __builtin_amdgcn_global_load_lds(
      (const __attribute__((address_space(1))) void*)g,
      (__attribute__((address_space(3))) void*)l, 16, 0, 0);
}

// ---------- np-bit-exact helpers (verified rounds 2-16: absmax 0) ----------
__device__ __forceinline__ float sqr_rn(float v) { return __fmul_rn(v, v); }

// ---------------- prep (codebook only): cnorm (np-exact) + cvt ----------------
__global__ __launch_bounds__(256) void vq_prepcb(const float* __restrict__ cb,
                                                 float* __restrict__ cnorm,
                                                 _Float16* __restrict__ cbsw,
                                                 int* __restrict__ wl_count,
                                                 double* __restrict__ accum) {
  const int t = threadIdx.x;
  if (blockIdx.x == 0 && t == 0) { *accum = 0.0; *wl_count = 0; }
  const int sub = t >> 4, lane16 = t & 15;
  const int h = lane16 >> 3, j = lane16 & 7;
  const int idx = blockIdx.x * 16 + sub;
  const float* p = cb + (size_t)idx * DDIM;

  float r = 0.f;
  const float* q = p + h * 128 + j;
#pragma unroll
  for (int i = 0; i < 16; ++i) r = __fadd_rn(r, sqr_rn(q[i * 8]));
  r = __fadd_rn(r, __shfl_xor(r, 1, 64));
  r = __fadd_rn(r, __shfl_xor(r, 2, 64));
  r = __fadd_rn(r, __shfl_xor(r, 4, 64));
  float sv = __fadd_rn(r, __shfl_xor(r, 8, 64));
  if (lane16 == 0) cnorm[idx] = sv;

  const int sw = idx & 7;
  _Float16* dst = cbsw + (size_t)idx * DDIM;
#pragma unroll
  for (int c = 0; c < 2; ++c) {
    int jj = lane16 + c * 16;
    float4 a4 = *reinterpret_cast<const float4*>(p + jj * 8);
    float4 b4 = *reinterpret_cast<const float4*>(p + jj * 8 + 4);
    union { half8 v; _Float16 hh[8]; } u;
    u.hh[0] = (_Float16)(a4.x * 256.0f); u.hh[1] = (_Float16)(a4.y * 256.0f);
    u.hh[2] = (_Float16)(a4.z * 256.0f); u.hh[3] = (_Float16)(a4.w * 256.0f);
    u.hh[4] = (_Float16)(b4.x * 256.0f); u.hh[5] = (_Float16)(b4.y * 256.0f);
    u.hh[6] = (_Float16)(b4.z * 256.0f); u.hh[7] = (_Float16)(b4.w * 256.0f);
    *reinterpret_cast<half8*>(dst + ((jj ^ sw) * 8)) = u.v;
  }
}

// ---------------- phase 1: f16 MFMA surrogate + min1/min2/argmin ----------------
// r13 K-loop upgraded: 3-buffer LDS ring -> ONE barrier per tile (top barrier is
// the WAR guard: all waves passing barrier(kt) finished compute(kt-1), so tile
// kt+2 may stage into buffer (kt-1)%3). Counted vmcnt(4): in-flight at top of
// kt = stage(kt)[old 4] + stage(kt+1)[new 4]; retire kt, retain kt+1.
// Second-min via v_med3_f32. S (row sumsq) fused into prologue (np-exact,
// byte-identical 16-lane decomposition, 4 passes of 32 rows).
__global__ __launch_bounds__(512, 2) void vq_score(const float* __restrict__ x,
                                                   const _Float16* __restrict__ cbsw,
                                                   float* __restrict__ Sarr,
                                                   const float* __restrict__ cnorm,
                                                   int* __restrict__ bestidx,
                                                   int* __restrict__ wl,
                                                   int* __restrict__ wl_count,
                                                   double* __restrict__ accum) {
  __shared__ _Float16 cbt[3][64 * DDIM];    // 3 x 32 KB code-tile ring
  __shared__ float cn[KC];                  // 16 KB: all code norms
  __shared__ float sS[BM];                  // np-exact row sumsq
  __shared__ float scrV1[4][BM];
  __shared__ float scrV2[4][BM];
  __shared__ int   scrI1[4][BM];
  __shared__ float wred[8];

  const int t = threadIdx.x;
  const int m0 = blockIdx.x * BM;
  const int lane = t & 63, w = t >> 6;
  const int rg = w >> 2, cg = w & 3;
  const int lo = lane & 15, hi = lane >> 4;

  // ---- prologue: stage tiles 0 and 1 (4 gload_lds each per thread) ----
#pragma unroll
  for (int j = 0; j < 4; ++j)
    gload_lds16(cbsw + 0 * 16384 + w * 2048 + j * 512 + lane * 8,
                &cbt[0][w * 2048 + j * 512]);
#pragma unroll
  for (int j = 0; j < 4; ++j)
    gload_lds16(cbsw + 1 * 16384 + w * 2048 + j * 512 + lane * 8,
                &cbt[1][w * 2048 + j * 512]);

  // ---- stage cn ----
#pragma unroll
  for (int i = 0; i < 2; ++i) {
    int fi = t + i * 512;
    *reinterpret_cast<float4*>(&cn[fi * 4]) =
        *reinterpret_cast<const float4*>(cnorm + fi * 4);
  }

  // ---- A fragments global -> registers (f16 cvt; AGPR residency is fine) ----
  half8 a[4][8];
#pragma unroll
  for (int s2 = 0; s2 < 4; ++s2) {
    const float* xr = x + (size_t)(m0 + rg * 64 + s2 * 16 + lo) * DDIM + hi * 8;
#pragma unroll
    for (int s = 0; s < 8; ++s) {
      float4 u0 = *reinterpret_cast<const float4*>(xr + s * 32);
      float4 u1 = *reinterpret_cast<const float4*>(xr + s * 32 + 4);
      union { half8 v; _Float16 h[8]; } uu;
      uu.h[0] = (_Float16)u0.x; uu.h[1] = (_Float16)u0.y;
      uu.h[2] = (_Float16)u0.z; uu.h[3] = (_Float16)u0.w;
      uu.h[4] = (_Float16)u1.x; uu.h[5] = (_Float16)u1.y;
      uu.h[6] = (_Float16)u1.z; uu.h[7] = (_Float16)u1.w;
      a[s2][s] = uu.v;
    }
  }

  // ---- np-exact S for this block's rows (verified 16-lane decomposition) ----
  {
    const int sub = t >> 4, lane16 = t & 15;
    const int h = lane16 >> 3, jj = lane16 & 7;
#pragma unroll
    for (int p = 0; p < 4; ++p) {
      int rowl = p * 32 + sub;
      const float* q = x + (size_t)(m0 + rowl) * DDIM + h * 128 + jj;
      float r = 0.f;
#pragma unroll
      for (int i = 0; i < 16; ++i) r = __fadd_rn(r, sqr_rn(q[i * 8]));
      r = __fadd_rn(r, __shfl_xor(r, 1, 64));
      r = __fadd_rn(r, __shfl_xor(r, 2, 64));
      r = __fadd_rn(r, __shfl_xor(r, 4, 64));
      float sv = __fadd_rn(r, __shfl_xor(r, 8, 64));
      if (lane16 == 0) { sS[rowl] = sv; Sarr[m0 + rowl] = sv; }
    }
  }

  const int code_l = cg * 16 + lo;          // code within 64-code tile
  const int bswz = (lo & 7) << 3;           // cvt stored chunk j at j^(code&7)

  float v1[4][4], v2[4][4]; int i1[4][4];
#pragma unroll
  for (int s2 = 0; s2 < 4; ++s2)
#pragma unroll
    for (int r = 0; r < 4; ++r) { v1[s2][r] = 3.4e38f; v2[s2][r] = 3.4e38f; i1[s2][r] = 0; }

  // one-time full sync: drains prologue (stages 0,1 + cn + A + S loads)
  __syncthreads();

  int cur = 0;
  for (int kt = 0; kt < KC / 64; ++kt) {
    // counted wait: tile kt landed; tile kt+1's 4 loads REMAIN in flight
    if (kt < KC / 64 - 1) asm volatile("s_waitcnt vmcnt(4)" ::: "memory");
    else                  asm volatile("s_waitcnt vmcnt(0)" ::: "memory");
    __builtin_amdgcn_s_barrier();           // raw barrier = WAR guard for buf (kt-1)%3

    if (kt < KC / 64 - 2) {
      int stg = cur + 2; if (stg >= 3) stg -= 3;   // == (kt-1)%3, free since barrier
#pragma unroll
      for (int j = 0; j < 4; ++j)
        gload_lds16(cbsw + (size_t)(kt + 2) * 16384 + w * 2048 + j * 512 + lane * 8,
                    &cbt[stg][w * 2048 + j * 512]);
    }

    const float C = cn[kt * 64 + code_l];
    f32x4 acc[4];
#pragma unroll
    for (int s2 = 0; s2 < 4; ++s2) acc[s2] = (f32x4){0.f, 0.f, 0.f, 0.f};
#pragma unroll
    for (int s = 0; s < 8; ++s) {
      half8 b = *reinterpret_cast<half8*>(
          &cbt[cur][(code_l * DDIM + s * 32 + hi * 8) ^ bswz]);
      acc[0] = __builtin_amdgcn_mfma_f32_16x16x32_f16(a[0][s], b, acc[0], 0, 0, 0);
      acc[1] = __builtin_amdgcn_mfma_f32_16x16x32_f16(a[1][s], b, acc[1], 0, 0, 0);
      acc[2] = __builtin_amdgcn_mfma_f32_16x16x32_f16(a[2][s], b, acc[2], 0, 0, 0);
      acc[3] = __builtin_amdgcn_mfma_f32_16x16x32_f16(a[3][s], b, acc[3], 0, 0, 0);
    }
    const int code = kt * 64 + code_l;
#pragma unroll
    for (int s2 = 0; s2 < 4; ++s2) {
#pragma unroll
      for (int r = 0; r < 4; ++r) {
        float sv = fmaf(acc[s2][r], -0.0078125f, C);   // s = C - 2E, acc = 256E
        // v2' = min(v2, max(v1, sv)) == med3(sv, v1, v2) since v1 <= v2
        v2[s2][r] = __builtin_amdgcn_fmed3f(sv, v1[s2][r], v2[s2][r]);
        bool lt = sv < v1[s2][r];
        if (lt) { v1[s2][r] = sv; i1[s2][r] = code; }
      }
    }
    cur = (cur == 2) ? 0 : cur + 1;
  }

  // ---- per-wave reduce across the 16 lo-lanes sharing each row ----
#pragma unroll
  for (int s2 = 0; s2 < 4; ++s2) {
#pragma unroll
    for (int r = 0; r < 4; ++r) {
      float v = v1[s2][r], u = v2[s2][r]; int ii = i1[s2][r];
#pragma unroll
      for (int m = 1; m <= 8; m <<= 1) {
        float ov = __shfl_xor(v, m, 64);
        int   oi = __shfl_xor(ii, m, 64);
        float ou = __shfl_xor(u, m, 64);
        float mx = fmaxf(v, ov);
        u = fminf(fminf(u, ou), mx);
        bool take = (ov < v) || (ov == v && oi < ii);
        if (take) { v = ov; ii = oi; }
      }
      if (lo == 0) {
        int rowl = rg * 64 + s2 * 16 + hi * 4 + r;
        scrV1[cg][rowl] = v;
        scrV2[cg][rowl] = u;
        scrI1[cg][rowl] = ii;
      }
    }
  }
  __syncthreads();

  // ---- combine the 4 code-quarter candidates per row (threads 0..127) ----
  float part = 0.f;
  if (t < BM) {
    float bv1 = 3.4e38f, bv2 = 3.4e38f; int bi1 = 0x7fffffff;
#pragma unroll
    for (int c = 0; c < 4; ++c) {
      float v = scrV1[c][t];
      float u = scrV2[c][t];
      int  ii = scrI1[c][t];
      float mx = fmaxf(bv1, v);
      bv2 = fminf(fminf(bv2, u), mx);
      if (v < bv1 || (v == bv1 && ii < bi1)) { bv1 = v; bi1 = ii; }
    }
    int row = m0 + t;
    bestidx[row] = bi1;
    float gap = bv2 - bv1;
    if (gap <= THRESH) {
      int pos = atomicAdd(wl_count, 1);
      if (pos >= WLCAP) part = __fadd_rn(sS[t], bv1);   // overflow fallback
      else wl[pos] = row;
    } else {
      part = __fadd_rn(sS[t], bv1);        // safe rows: approx D_min to loss
    }
  }
#pragma unroll
  for (int off = 32; off >= 1; off >>= 1) part += __shfl_down(part, off, 64);
  if (lane == 0) wred[w] = part;
  __syncthreads();
  if (t == 0) {
    double s = 0.0;
#pragma unroll
    for (int i = 0; i < 8; ++i) s += (double)wred[i];
    atomicAdd(accum, s);
  }
}

// ---------------- phase 2: np-bit-exact rescore, 8 rows/group (verified) ----
__global__ __launch_bounds__(256) void vq_rescore(const float* __restrict__ x,
                                                  const float* __restrict__ cb,
                                                  const float* __restrict__ Sarr,
                                                  const float* __restrict__ cnorm,
                                                  const int* __restrict__ wl,
                                                  const int* __restrict__ wl_count,
                                                  float* __restrict__ pD,
                                                  int* __restrict__ pI) {
  const int cnt = min(*wl_count, WLCAP);
  if (cnt == 0) return;
  const int ngroups = (cnt + 7) >> 3;
  const int nitems = ngroups * 16;

  __shared__ float xs[8][260];
  __shared__ int rsh[8];
  __shared__ float scrv[8][4];
  __shared__ int   scri[8][4];

  const int t = threadIdx.x;
  const int lane = t & 63, w = t >> 6;

  for (int item = blockIdx.x; item < nitems; item += RGRID) {
    const int g = item >> 4, chunk = item & 15;
    __syncthreads();
    if (t < 8) { int e = g * 8 + t; rsh[t] = wl[(e < cnt) ? e : g * 8]; }
    __syncthreads();
#pragma unroll
    for (int j = 0; j < 2; ++j) {
      int fi = t + j * 256, i = fi >> 6, dq = fi & 63;
      *reinterpret_cast<float4*>(&xs[i][dq * 4]) =
          *reinterpret_cast<const float4*>(x + (size_t)rsh[i] * DDIM + dq * 4);
    }
    __syncthreads();

    const int code = chunk * 256 + t;
    const float* cp = cb + (size_t)code * DDIM;
    const float C = cnorm[code];

    float acc[8][4];
#pragma unroll
    for (int i = 0; i < 8; ++i)
#pragma unroll
      for (int l = 0; l < 4; ++l) acc[i][l] = 0.f;

#pragma unroll 4
    for (int dq = 0; dq < 64; ++dq) {
      float4 cv = *reinterpret_cast<const float4*>(cp + dq * 4);
#pragma unroll
      for (int i = 0; i < 8; ++i) {
        float4 xv = *reinterpret_cast<float4*>(&xs[i][dq * 4]);
        acc[i][0] = __fadd_rn(acc[i][0], __fmul_rn(xv.x, cv.x));
        acc[i][1] = __fadd_rn(acc[i][1], __fmul_rn(xv.y, cv.y));
        acc[i][2] = __fadd_rn(acc[i][2], __fmul_rn(xv.z, cv.z));
        acc[i][3] = __fadd_rn(acc[i][3], __fmul_rn(xv.w, cv.w));
      }
    }

#pragma unroll
    for (int i = 0; i < 8; ++i) {
      float e = __fadd_rn(__fadd_rn(acc[i][0], acc[i][1]),
                          __fadd_rn(acc[i][2], acc[i][3]));
      float Sv = Sarr[rsh[i]];
      float D = __fadd_rn(__fsub_rn(Sv, __fmul_rn(2.0f, e)), C);
      float v = D; int ii = code;
#pragma unroll
      for (int m = 1; m <= 32; m <<= 1) {
        float ov = __shfl_xor(v, m, 64);
        int   oi = __shfl_xor(ii, m, 64);
        if (ov < v || (ov == v && oi < ii)) { v = ov; ii = oi; }
      }
      if (lane == 0) { scrv[i][w] = v; scri[i][w] = ii; }
    }
    __syncthreads();
    if (t < 8) {
      float bv = 3.4e38f; int bi = 0x7fffffff;
#pragma unroll
      for (int c = 0; c < 4; ++c) {
        float v = scrv[t][c]; int ii = scri[t][c];
        if (v < bv || (v == bv && ii < bi)) { bv = v; bi = ii; }
      }
      int rpos = g * 8 + t;
      if (rpos < cnt) { pD[rpos * 16 + chunk] = bv; pI[rpos * 16 + chunk] = bi; }
    }
  }
}

// ---------------- combine (single block): chunk-min + bestidx + FUSED loss ----
__global__ __launch_bounds__(256) void vq_combine(const int* __restrict__ wl,
                                                  const int* __restrict__ wl_count,
                                                  const float* __restrict__ pD,
                                                  const int* __restrict__ pI,
                                                  int* __restrict__ bestidx,
                                                  double* __restrict__ accum,
                                                  float* __restrict__ out) {
  __shared__ double dred[4];
  const int cnt = min(*wl_count, WLCAP);
  const int t = threadIdx.x;

  double s = 0.0;
  for (int r = t; r < cnt; r += 256) {
    float bv = 3.4e38f; int bi = 0x7fffffff;
#pragma unroll
    for (int c = 0; c < 16; ++c) {
      float v = pD[r * 16 + c]; int ii = pI[r * 16 + c];
      if (v < bv || (v == bv && ii < bi)) { bv = v; bi = ii; }
    }
    bestidx[wl[r]] = bi;
    s += (double)bv;                        // exact D_min for rescored rows
  }
#pragma unroll
  for (int off = 32; off >= 1; off >>= 1) s += __shfl_down(s, off, 64);
  if ((t & 63) == 0) dred[t >> 6] = s;
  __syncthreads();
  if (t == 0) {
    double tot = (dred[0] + dred[1]) + (dred[2] + dred[3]);
    double prev = atomicAdd(accum, tot);    // last accum writer -> final value
    out[ZELEMS] = (float)(1.25 * (prev + tot) / (double)ZELEMS);
  }
}

// ---------------- phase 3: emit z_q_st, indices (verified) ----------------
__global__ __launch_bounds__(256) void vq_emit(const float* __restrict__ x,
                                               const float* __restrict__ cb,
                                               const int* __restrict__ bestidx,
                                               float* __restrict__ out) {
  __shared__ int ish[64];
  const int t = threadIdx.x;
  const int m0 = blockIdx.x * 64;
  if (t < 64) {
    int ii = bestidx[m0 + t];
    ish[t] = ii;
    out[(size_t)ZELEMS + 1 + m0 + t] = (float)ii;
  }
  __syncthreads();
#pragma unroll
  for (int i = 0; i < 16; ++i) {
    int fi = t + i * 256;
    int row = fi >> 6, dc = fi & 63;
    int code = ish[row];
    float4 c4 = *reinterpret_cast<const float4*>(cb + (size_t)code * DDIM + dc * 4);
    float4 x4 = *reinterpret_cast<const float4*>(x + (size_t)(m0 + row) * DDIM + dc * 4);
    float4 o;
    o.x = __fadd_rn(x4.x, __fsub_rn(c4.x, x4.x));
    o.y = __fadd_rn(x4.y, __fsub_rn(c4.y, x4.y));
    o.z = __fadd_rn(x4.z, __fsub_rn(c4.z, x4.z));
    o.w = __fadd_rn(x4.w, __fsub_rn(c4.w, x4.w));
    *reinterpret_cast<float4*>(out + (size_t)(m0 + row) * DDIM + dc * 4) = o;
  }
}

extern "C" void kernel_launch(void* const* d_in, const int* in_sizes, int n_in,
                              void* d_out, int out_size, void* d_ws, size_t ws_size,
                              hipStream_t stream) {
  const float* x  = (const float*)d_in[0];
  const float* cb = (const float*)d_in[1];
  float* out = (float*)d_out;

  char* ws = (char*)d_ws;
  float*     S        = (float*)(ws + 0);           // 128 KB
  float*     cnorm    = (float*)(ws + 131072);      // 16 KB
  int*       bestidx  = (int*)  (ws + 147456);      // 128 KB
  int*       wl       = (int*)  (ws + 278528);      // 32 KB
  int*       wl_count = (int*)  (ws + 311296);
  double*    accum    = (double*)(ws + 311312);
  float*     pD       = (float*)(ws + 315392);      // 512 KB
  int*       pI       = (int*)  (ws + 839680);      // 512 KB
  _Float16*  cbsw     = (_Float16*)(ws + 1363968);  // 2 MB, chunk-swizzled f16 codebook

  vq_prepcb<<<KC / 16, 256, 0, stream>>>(cb, cnorm, cbsw, wl_count, accum);
  vq_score<<<MTOT / BM, 512, 0, stream>>>(x, cbsw, S, cnorm, bestidx, wl, wl_count, accum);
  vq_rescore<<<RGRID, 256, 0, stream>>>(x, cb, S, cnorm, wl, wl_count, pD, pI);
  vq_combine<<<1, 256, 0, stream>>>(wl, wl_count, pD, pI, bestidx, accum, out);
  vq_emit<<<MTOT / 64, 256, 0, stream>>>(x, cb, bestidx, out);
}

// Round 18
// 164.180 us; speedup vs baseline: 1.1458x; 1.1458x over previous
//
#include <hip/hip_runtime.h>

#define MTOT 32768
#define KC   4096
#define DDIM 256
#define BM   128          // rows per block, phase 1
#define ZELEMS (MTOT * DDIM)
#define THRESH 2.0e-4f
#define WLCAP 8192
#define RGRID 2048        // rescore grid

typedef _Float16 half8 __attribute__((ext_vector_type(8)));
typedef float f32x4 __attribute__((ext_vector_type(4)));

__device__ __forceinline__ void gload_lds16(const void* g, void* l) {
  __builtin_amdgcn_global_load_lds(
      (const __attribute__((address_space(1))) void*)g,
      (__attribute__((address_space(3))) void*)l, 16, 0, 0);
}

// ---------- np-bit-exact helpers (verified rounds 2-17: absmax 0) ----------
__device__ __forceinline__ float sqr_rn(float v) { return __fmul_rn(v, v); }

// ---------------- fused prep+cvt ----------------
// blocks [0,2048): x rows -> S. blocks [2048,2304): codes -> cnorm + cbsw.
// cbsw per-tile layout is FRAGMENT-MAJOR (f16 units within tile kt):
//   off(s,cg,hi,lo) = s*2048 + cg*512 + hi*128 + lo*8
// so a wave's (s) B-fragment read is uniform-base + lane*16B: conflict-free.
__global__ __launch_bounds__(256) void vq_prep2(const float* __restrict__ x,
                                                const float* __restrict__ cb,
                                                float* __restrict__ S,
                                                float* __restrict__ cnorm,
                                                _Float16* __restrict__ cbsw,
                                                int* __restrict__ wl_count,
                                                double* __restrict__ accum) {
  const int t = threadIdx.x;
  if (blockIdx.x == 0 && t == 0) { *accum = 0.0; *wl_count = 0; }
  const int sub = t >> 4, lane16 = t & 15;
  const int h = lane16 >> 3, j = lane16 & 7;
  const bool isrow = blockIdx.x < 2048;
  const int idx = (isrow ? blockIdx.x : blockIdx.x - 2048) * 16 + sub;
  const float* p = (isrow ? x + (size_t)idx * DDIM : cb + (size_t)idx * DDIM);

  float r = 0.f;
  const float* q = p + h * 128 + j;
#pragma unroll
  for (int i = 0; i < 16; ++i) r = __fadd_rn(r, sqr_rn(q[i * 8]));
  r = __fadd_rn(r, __shfl_xor(r, 1, 64));
  r = __fadd_rn(r, __shfl_xor(r, 2, 64));
  r = __fadd_rn(r, __shfl_xor(r, 4, 64));
  float sv = __fadd_rn(r, __shfl_xor(r, 8, 64));
  if (lane16 == 0) {
    if (isrow) S[idx] = sv; else cnorm[idx] = sv;
  }

  if (!isrow) {
    const int kt = idx >> 6, code_l = idx & 63;
    const int cg = code_l >> 4, lo = code_l & 15;
    _Float16* base = cbsw + (size_t)kt * 16384 + cg * 512 + lo * 8;
#pragma unroll
    for (int c = 0; c < 2; ++c) {
      int jj = lane16 + c * 16;              // chunk: d = jj*8 .. +8
      int s = jj >> 2, hi = jj & 3;
      float4 a4 = *reinterpret_cast<const float4*>(p + jj * 8);
      float4 b4 = *reinterpret_cast<const float4*>(p + jj * 8 + 4);
      union { half8 v; _Float16 hh[8]; } u;
      u.hh[0] = (_Float16)(a4.x * 256.0f); u.hh[1] = (_Float16)(a4.y * 256.0f);
      u.hh[2] = (_Float16)(a4.z * 256.0f); u.hh[3] = (_Float16)(a4.w * 256.0f);
      u.hh[4] = (_Float16)(b4.x * 256.0f); u.hh[5] = (_Float16)(b4.y * 256.0f);
      u.hh[6] = (_Float16)(b4.z * 256.0f); u.hh[7] = (_Float16)(b4.w * 256.0f);
      *reinterpret_cast<half8*>(base + s * 2048 + hi * 128) = u.v;
    }
  }
}

// ---------------- phase 1: f16 MFMA surrogate + min1/min2/argmin ----------------
// r13/r16 K-loop (measured 105.9us) with the ONLY change being the conflict-free
// fragment-major B-read: ds_read_b128 at uniform base + lane*16 (zero conflicts,
// no XOR address math). Staging copy is byte-identical (linear tile copy).
__global__ __launch_bounds__(512, 2) void vq_score(const float* __restrict__ x,
                                                   const _Float16* __restrict__ cbsw,
                                                   const float* __restrict__ Sarr,
                                                   const float* __restrict__ cnorm,
                                                   int* __restrict__ bestidx,
                                                   int* __restrict__ wl,
                                                   int* __restrict__ wl_count,
                                                   double* __restrict__ accum) {
  __shared__ _Float16 cbt[2][64 * DDIM];    // 2 x 32 KB double-buffered code tile
  __shared__ float cn[KC];                  // 16 KB: all code norms
  __shared__ float scrV1[4][BM];
  __shared__ float scrV2[4][BM];
  __shared__ int   scrI1[4][BM];
  __shared__ float wred[8];

  const int t = threadIdx.x;
  const int m0 = blockIdx.x * BM;
  const int lane = t & 63, w = t >> 6;
  const int rg = w >> 2, cg = w & 3;
  const int lo = lane & 15, hi = lane >> 4;

  // ---- prologue: stage tiles 0 and 1 (4 gload_lds each per thread) ----
#pragma unroll
  for (int j = 0; j < 4; ++j)
    gload_lds16(cbsw + 0 * 16384 + w * 2048 + j * 512 + lane * 8,
                &cbt[0][w * 2048 + j * 512]);
#pragma unroll
  for (int j = 0; j < 4; ++j)
    gload_lds16(cbsw + 1 * 16384 + w * 2048 + j * 512 + lane * 8,
                &cbt[1][w * 2048 + j * 512]);

  // ---- stage cn (LDS; removes per-tile global C loads from the vmcnt stream) ----
#pragma unroll
  for (int i = 0; i < 2; ++i) {
    int fi = t + i * 512;
    *reinterpret_cast<float4*>(&cn[fi * 4]) =
        *reinterpret_cast<const float4*>(cnorm + fi * 4);
  }

  // ---- A fragments global -> registers (f16 cvt; AGPR residency is fine) ----
  half8 a[4][8];
#pragma unroll
  for (int s2 = 0; s2 < 4; ++s2) {
    const float* xr = x + (size_t)(m0 + rg * 64 + s2 * 16 + lo) * DDIM + hi * 8;
#pragma unroll
    for (int s = 0; s < 8; ++s) {
      float4 u0 = *reinterpret_cast<const float4*>(xr + s * 32);
      float4 u1 = *reinterpret_cast<const float4*>(xr + s * 32 + 4);
      union { half8 v; _Float16 h[8]; } uu;
      uu.h[0] = (_Float16)u0.x; uu.h[1] = (_Float16)u0.y;
      uu.h[2] = (_Float16)u0.z; uu.h[3] = (_Float16)u0.w;
      uu.h[4] = (_Float16)u1.x; uu.h[5] = (_Float16)u1.y;
      uu.h[6] = (_Float16)u1.z; uu.h[7] = (_Float16)u1.w;
      a[s2][s] = uu.v;
    }
  }

  const int code_l = cg * 16 + lo;          // code within 64-code tile
  // conflict-free B-read base (f16 units): s*2048 + cg*512 + lane*8
  const int bbase = cg * 512 + lane * 8;

  float v1[4][4], v2[4][4]; int i1[4][4];
#pragma unroll
  for (int s2 = 0; s2 < 4; ++s2)
#pragma unroll
    for (int r = 0; r < 4; ++r) { v1[s2][r] = 3.4e38f; v2[s2][r] = 3.4e38f; i1[s2][r] = 0; }

  // one-time full sync: drains prologue stages (tiles 0,1) + publishes cn
  __syncthreads();

  for (int kt = 0; kt < KC / 64; ++kt) {
    const int cur = kt & 1;
    // counted wait: tile kt landed; tile kt+1's 4 loads REMAIN in flight
    if (kt < KC / 64 - 1) asm volatile("s_waitcnt vmcnt(4)" ::: "memory");
    else                  asm volatile("s_waitcnt vmcnt(0)" ::: "memory");
    __builtin_amdgcn_s_barrier();           // raw: no auto vmcnt drain

    const float C = cn[kt * 64 + code_l];
    f32x4 acc[4];
#pragma unroll
    for (int s2 = 0; s2 < 4; ++s2) acc[s2] = (f32x4){0.f, 0.f, 0.f, 0.f};
#pragma unroll
    for (int s = 0; s < 8; ++s) {
      half8 b = *reinterpret_cast<half8*>(&cbt[cur][s * 2048 + bbase]);
      acc[0] = __builtin_amdgcn_mfma_f32_16x16x32_f16(a[0][s], b, acc[0], 0, 0, 0);
      acc[1] = __builtin_amdgcn_mfma_f32_16x16x32_f16(a[1][s], b, acc[1], 0, 0, 0);
      acc[2] = __builtin_amdgcn_mfma_f32_16x16x32_f16(a[2][s], b, acc[2], 0, 0, 0);
      acc[3] = __builtin_amdgcn_mfma_f32_16x16x32_f16(a[3][s], b, acc[3], 0, 0, 0);
    }
    const int code = kt * 64 + code_l;
#pragma unroll
    for (int s2 = 0; s2 < 4; ++s2) {
#pragma unroll
      for (int r = 0; r < 4; ++r) {
        float sv = fmaf(acc[s2][r], -0.0078125f, C);   // s = C - 2E, acc = 256E
        float mx = fmaxf(v1[s2][r], sv);               // 2nd-min candidate
        v2[s2][r] = fminf(v2[s2][r], mx);
        bool lt = sv < v1[s2][r];
        if (lt) { v1[s2][r] = sv; i1[s2][r] = code; }
      }
    }

    __builtin_amdgcn_s_barrier();           // all waves done reading cbt[cur]
    if (kt < KC / 64 - 2) {
      // re-stage cbt[cur] with tile kt+2 (issued AFTER barrier: WAR-safe)
#pragma unroll
      for (int j = 0; j < 4; ++j)
        gload_lds16(cbsw + (size_t)(kt + 2) * 16384 + w * 2048 + j * 512 + lane * 8,
                    &cbt[cur][w * 2048 + j * 512]);
    }
  }

  // ---- per-wave reduce across the 16 lo-lanes sharing each row ----
#pragma unroll
  for (int s2 = 0; s2 < 4; ++s2) {
#pragma unroll
    for (int r = 0; r < 4; ++r) {
      float v = v1[s2][r], u = v2[s2][r]; int ii = i1[s2][r];
#pragma unroll
      for (int m = 1; m <= 8; m <<= 1) {
        float ov = __shfl_xor(v, m, 64);
        int   oi = __shfl_xor(ii, m, 64);
        float ou = __shfl_xor(u, m, 64);
        float mx = fmaxf(v, ov);
        u = fminf(fminf(u, ou), mx);
        bool take = (ov < v) || (ov == v && oi < ii);
        if (take) { v = ov; ii = oi; }
      }
      if (lo == 0) {
        int rowl = rg * 64 + s2 * 16 + hi * 4 + r;
        scrV1[cg][rowl] = v;
        scrV2[cg][rowl] = u;
        scrI1[cg][rowl] = ii;
      }
    }
  }
  __syncthreads();

  // ---- combine the 4 code-quarter candidates per row (threads 0..127) ----
  float part = 0.f;
  if (t < BM) {
    float bv1 = 3.4e38f, bv2 = 3.4e38f; int bi1 = 0x7fffffff;
#pragma unroll
    for (int c = 0; c < 4; ++c) {
      float v = scrV1[c][t];
      float u = scrV2[c][t];
      int  ii = scrI1[c][t];
      float mx = fmaxf(bv1, v);
      bv2 = fminf(fminf(bv2, u), mx);
      if (v < bv1 || (v == bv1 && ii < bi1)) { bv1 = v; bi1 = ii; }
    }
    int row = m0 + t;
    bestidx[row] = bi1;
    float gap = bv2 - bv1;
    if (gap <= THRESH) {
      int pos = atomicAdd(wl_count, 1);
      if (pos >= WLCAP) part = __fadd_rn(Sarr[row], bv1);   // overflow fallback
      else wl[pos] = row;
    } else {
      part = __fadd_rn(Sarr[row], bv1);    // safe rows: approx D_min to loss
    }
  }
#pragma unroll
  for (int off = 32; off >= 1; off >>= 1) part += __shfl_down(part, off, 64);
  if (lane == 0) wred[w] = part;
  __syncthreads();
  if (t == 0) {
    double s = 0.0;
#pragma unroll
    for (int i = 0; i < 8; ++i) s += (double)wred[i];
    atomicAdd(accum, s);
  }
}

// ---------------- phase 2: np-bit-exact rescore, 8 rows/group (verified) ----
__global__ __launch_bounds__(256) void vq_rescore(const float* __restrict__ x,
                                                  const float* __restrict__ cb,
                                                  const float* __restrict__ Sarr,
                                                  const float* __restrict__ cnorm,
                                                  const int* __restrict__ wl,
                                                  const int* __restrict__ wl_count,
                                                  float* __restrict__ pD,
                                                  int* __restrict__ pI) {
  const int cnt = min(*wl_count, WLCAP);
  if (cnt == 0) return;
  const int ngroups = (cnt + 7) >> 3;
  const int nitems = ngroups * 16;

  __shared__ float xs[8][260];
  __shared__ int rsh[8];
  __shared__ float scrv[8][4];
  __shared__ int   scri[8][4];

  const int t = threadIdx.x;
  const int lane = t & 63, w = t >> 6;

  for (int item = blockIdx.x; item < nitems; item += RGRID) {
    const int g = item >> 4, chunk = item & 15;
    __syncthreads();
    if (t < 8) { int e = g * 8 + t; rsh[t] = wl[(e < cnt) ? e : g * 8]; }
    __syncthreads();
#pragma unroll
    for (int j = 0; j < 2; ++j) {
      int fi = t + j * 256, i = fi >> 6, dq = fi & 63;
      *reinterpret_cast<float4*>(&xs[i][dq * 4]) =
          *reinterpret_cast<const float4*>(x + (size_t)rsh[i] * DDIM + dq * 4);
    }
    __syncthreads();

    const int code = chunk * 256 + t;
    const float* cp = cb + (size_t)code * DDIM;
    const float C = cnorm[code];

    float acc[8][4];
#pragma unroll
    for (int i = 0; i < 8; ++i)
#pragma unroll
      for (int l = 0; l < 4; ++l) acc[i][l] = 0.f;

#pragma unroll 4
    for (int dq = 0; dq < 64; ++dq) {
      float4 cv = *reinterpret_cast<const float4*>(cp + dq * 4);
#pragma unroll
      for (int i = 0; i < 8; ++i) {
        float4 xv = *reinterpret_cast<float4*>(&xs[i][dq * 4]);
        acc[i][0] = __fadd_rn(acc[i][0], __fmul_rn(xv.x, cv.x));
        acc[i][1] = __fadd_rn(acc[i][1], __fmul_rn(xv.y, cv.y));
        acc[i][2] = __fadd_rn(acc[i][2], __fmul_rn(xv.z, cv.z));
        acc[i][3] = __fadd_rn(acc[i][3], __fmul_rn(xv.w, cv.w));
      }
    }

#pragma unroll
    for (int i = 0; i < 8; ++i) {
      float e = __fadd_rn(__fadd_rn(acc[i][0], acc[i][1]),
                          __fadd_rn(acc[i][2], acc[i][3]));
      float Sv = Sarr[rsh[i]];
      float D = __fadd_rn(__fsub_rn(Sv, __fmul_rn(2.0f, e)), C);
      float v = D; int ii = code;
#pragma unroll
      for (int m = 1; m <= 32; m <<= 1) {
        float ov = __shfl_xor(v, m, 64);
        int   oi = __shfl_xor(ii, m, 64);
        if (ov < v || (ov == v && oi < ii)) { v = ov; ii = oi; }
      }
      if (lane == 0) { scrv[i][w] = v; scri[i][w] = ii; }
    }
    __syncthreads();
    if (t < 8) {
      float bv = 3.4e38f; int bi = 0x7fffffff;
#pragma unroll
      for (int c = 0; c < 4; ++c) {
        float v = scrv[t][c]; int ii = scri[t][c];
        if (v < bv || (v == bv && ii < bi)) { bv = v; bi = ii; }
      }
      int rpos = g * 8 + t;
      if (rpos < cnt) { pD[rpos * 16 + chunk] = bv; pI[rpos * 16 + chunk] = bi; }
    }
  }
}

// ---------------- combine (single block): chunk-min + bestidx + FUSED loss ----
__global__ __launch_bounds__(256) void vq_combine(const int* __restrict__ wl,
                                                  const int* __restrict__ wl_count,
                                                  const float* __restrict__ pD,
                                                  const int* __restrict__ pI,
                                                  int* __restrict__ bestidx,
                                                  double* __restrict__ accum,
                                                  float* __restrict__ out) {
  __shared__ double dred[4];
  const int cnt = min(*wl_count, WLCAP);
  const int t = threadIdx.x;

  double s = 0.0;
  for (int r = t; r < cnt; r += 256) {
    float bv = 3.4e38f; int bi = 0x7fffffff;
#pragma unroll
    for (int c = 0; c < 16; ++c) {
      float v = pD[r * 16 + c]; int ii = pI[r * 16 + c];
      if (v < bv || (v == bv && ii < bi)) { bv = v; bi = ii; }
    }
    bestidx[wl[r]] = bi;
    s += (double)bv;                        // exact D_min for rescored rows
  }
#pragma unroll
  for (int off = 32; off >= 1; off >>= 1) s += __shfl_down(s, off, 64);
  if ((t & 63) == 0) dred[t >> 6] = s;
  __syncthreads();
  if (t == 0) {
    double tot = (dred[0] + dred[1]) + (dred[2] + dred[3]);
    double prev = atomicAdd(accum, tot);    // last accum writer -> final value
    out[ZELEMS] = (float)(1.25 * (prev + tot) / (double)ZELEMS);
  }
}

// ---------------- phase 3: emit z_q_st, indices (verified) ----------------
__global__ __launch_bounds__(256) void vq_emit(const float* __restrict__ x,
                                               const float* __restrict__ cb,
                                               const int* __restrict__ bestidx,
                                               float* __restrict__ out) {
  __shared__ int ish[64];
  const int t = threadIdx.x;
  const int m0 = blockIdx.x * 64;
  if (t < 64) {
    int ii = bestidx[m0 + t];
    ish[t] = ii;
    out[(size_t)ZELEMS + 1 + m0 + t] = (float)ii;
  }
  __syncthreads();
#pragma unroll
  for (int i = 0; i < 16; ++i) {
    int fi = t + i * 256;
    int row = fi >> 6, dc = fi & 63;
    int code = ish[row];
    float4 c4 = *reinterpret_cast<const float4*>(cb + (size_t)code * DDIM + dc * 4);
    float4 x4 = *reinterpret_cast<const float4*>(x + (size_t)(m0 + row) * DDIM + dc * 4);
    float4 o;
    o.x = __fadd_rn(x4.x, __fsub_rn(c4.x, x4.x));
    o.y = __fadd_rn(x4.y, __fsub_rn(c4.y, x4.y));
    o.z = __fadd_rn(x4.z, __fsub_rn(c4.z, x4.z));
    o.w = __fadd_rn(x4.w, __fsub_rn(c4.w, x4.w));
    *reinterpret_cast<float4*>(out + (size_t)(m0 + row) * DDIM + dc * 4) = o;
  }
}

extern "C" void kernel_launch(void* const* d_in, const int* in_sizes, int n_in,
                              void* d_out, int out_size, void* d_ws, size_t ws_size,
                              hipStream_t stream) {
  const float* x  = (const float*)d_in[0];
  const float* cb = (const float*)d_in[1];
  float* out = (float*)d_out;

  char* ws = (char*)d_ws;
  float*     S        = (float*)(ws + 0);           // 128 KB
  float*     cnorm    = (float*)(ws + 131072);      // 16 KB
  int*       bestidx  = (int*)  (ws + 147456);      // 128 KB
  int*       wl       = (int*)  (ws + 278528);      // 32 KB
  int*       wl_count = (int*)  (ws + 311296);
  double*    accum    = (double*)(ws + 311312);
  float*     pD       = (float*)(ws + 315392);      // 512 KB
  int*       pI       = (int*)  (ws + 839680);      // 512 KB
  _Float16*  cbsw     = (_Float16*)(ws + 1363968);  // 2 MB, fragment-major f16 codebook

  vq_prep2<<<2304, 256, 0, stream>>>(x, cb, S, cnorm, cbsw, wl_count, accum);
  vq_score<<<MTOT / BM, 512, 0, stream>>>(x, cbsw, S, cnorm, bestidx, wl, wl_count, accum);
  vq_rescore<<<RGRID, 256, 0, stream>>>(x, cb, S, cnorm, wl, wl_count, pD, pI);
  vq_combine<<<1, 256, 0, stream>>>(wl, wl_count, pD, pI, bestidx, accum, out);
  vq_emit<<<MTOT / 64, 256, 0, stream>>>(x, cb, bestidx, out);
}